// Round 1
// baseline (32886.438 us; speedup 1.0000x reference)
//
#include <hip/hip_runtime.h>
#include <hip/hip_fp16.h>

#define HH   51
#define H4   204
#define TSEQ 2048
#define FUT  64
#define TT   (TSEQ + FUT)   // 2112
#define RPB  32             // rows (batch) per block
#define NTH  1024
#define WROWS 224           // padded weight rows (>= 204 + 13 garbage margin)

__device__ __forceinline__ float sigm(float z) {
    return 1.0f / (1.0f + __expf(-z));
}

__global__ __launch_bounds__(NTH)
void lstm_kernel(const float* __restrict__ x,
                 const float* __restrict__ Wih1, const float* __restrict__ Whh1,
                 const float* __restrict__ bih1, const float* __restrict__ bhh1,
                 const float* __restrict__ Wih2, const float* __restrict__ Whh2,
                 const float* __restrict__ bih2, const float* __restrict__ bhh2,
                 const float* __restrict__ Wout, const float* __restrict__ bout,
                 float* __restrict__ out)
{
    // LDS: weights (f16), biases/wout (f32), per-row h buffer (f32)
    __shared__ __half W1[WROWS][52];   // [j][k]: k=0 -> W_ih1[j], k=1..51 -> W_hh1[j][k-1]
    __shared__ __half W2[WROWS][52];   // [j][k]: k=0 -> 0,        k=1..51 -> (W_ih2+W_hh2)[j][k-1]
    __shared__ float bias1[WROWS];
    __shared__ float bias2[WROWS];
    __shared__ float wout_s[52];       // [0]=0, [1..51] = W_out
    __shared__ float hbuf[RPB][52];    // [r][0] = x_t, [r][1..51] = h1
    __shared__ float xprev[RPB];       // previous output (for future feedback)

    const int tid = threadIdx.x;
    const int r   = tid >> 5;          // row within block [0,32)
    const int k0  = tid & 31;          // element slot [0,32)
    const int rb  = blockIdx.x * RPB;
    const int row = rb + r;
    const bool has_b = (k0 < HH - 32); // k0 < 19: second element k0+32 valid

    // ---- one-time weight staging ----
    for (int idx = tid; idx < WROWS * 52; idx += NTH) {
        const int j = idx / 52, k = idx % 52;
        float w1 = 0.f, w2 = 0.f;
        if (j < H4) {
            if (k == 0) { w1 = Wih1[j]; w2 = 0.f; }
            else {
                const int o = j * HH + (k - 1);
                w1 = Whh1[o];
                w2 = Wih2[o] + Whh2[o];
            }
        }
        W1[j][k] = __float2half(w1);
        W2[j][k] = __float2half(w2);
    }
    for (int idx = tid; idx < WROWS; idx += NTH) {
        bias1[idx] = (idx < H4) ? (bih1[idx] + bhh1[idx]) : 0.f;
        bias2[idx] = (idx < H4) ? (bih2[idx] + bhh2[idx]) : 0.f;
    }
    if (tid < 52) wout_s[tid] = (tid >= 1 && tid <= HH) ? Wout[tid - 1] : 0.f;
    for (int idx = tid; idx < RPB * 52; idx += NTH) (&hbuf[0][0])[idx] = 0.f;
    const float bo = bout[0];
    __syncthreads();

    // fixed gate-quadruple row pointers for this thread (j = q*51 + k0 [+32])
    const __half2* W1a[4]; const __half2* W1b[4];
    const __half2* W2a[4]; const __half2* W2b[4];
    #pragma unroll
    for (int q = 0; q < 4; ++q) {
        const int ja = q * HH + k0;
        const int jb = ja + 32;        // may exceed 203; pad rows are zero
        W1a[q] = (const __half2*)W1[ja];
        W1b[q] = (const __half2*)W1[jb];
        W2a[q] = (const __half2*)W2[ja];
        W2b[q] = (const __half2*)W2[jb];
    }

    float c_a = 0.f, c_b = 0.f;

    for (int t = 0; t < TT; ++t) {
        // stage x_t (or fed-back output) into hbuf[:,0]
        if (tid < RPB)
            hbuf[tid][0] = (t < TSEQ) ? x[(rb + tid) * TSEQ + t] : xprev[tid];
        __syncthreads();

        // ---------------- layer 1: gates for k0 (and k0+32) ----------------
        float acc[8];
        #pragma unroll
        for (int q = 0; q < 4; ++q) {
            acc[q]     = bias1[q * HH + k0];
            acc[4 + q] = bias1[q * HH + k0 + 32];
        }
        for (int kk = 0; kk < 26; ++kk) {
            const float2 hv = *(const float2*)&hbuf[r][2 * kk];
            #pragma unroll
            for (int q = 0; q < 4; ++q) {
                const float2 wa = __half22float2(W1a[q][kk]);
                const float2 wb = __half22float2(W1b[q][kk]);
                acc[q]     += wa.x * hv.x + wa.y * hv.y;
                acc[4 + q] += wb.x * hv.x + wb.y * hv.y;
            }
        }
        {
            const float ig = sigm(acc[0]), fg = sigm(acc[1]);
            const float gg = tanhf(acc[2]), og = sigm(acc[3]);
            c_a = fg * c_a + ig * gg;
            hbuf[r][1 + k0] = og * tanhf(c_a);
        }
        if (has_b) {
            const float ig = sigm(acc[4]), fg = sigm(acc[5]);
            const float gg = tanhf(acc[6]), og = sigm(acc[7]);
            c_b = fg * c_b + ig * gg;
            hbuf[r][1 + k0 + 32] = og * tanhf(c_b);
        }
        __syncthreads();

        // ---------------- layer 2 (emit) + output ----------------
        float ac2[8];
        #pragma unroll
        for (int q = 0; q < 4; ++q) {
            ac2[q]     = bias2[q * HH + k0];
            ac2[4 + q] = bias2[q * HH + k0 + 32];
        }
        for (int kk = 0; kk < 26; ++kk) {
            const float2 hv = *(const float2*)&hbuf[r][2 * kk];
            #pragma unroll
            for (int q = 0; q < 4; ++q) {
                const float2 wa = __half22float2(W2a[q][kk]);
                const float2 wb = __half22float2(W2b[q][kk]);
                ac2[q]     += wa.x * hv.x + wa.y * hv.y;
                ac2[4 + q] += wb.x * hv.x + wb.y * hv.y;
            }
        }
        float part;
        {
            const float ig = sigm(ac2[0]), fg = sigm(ac2[1]);
            const float gg = tanhf(ac2[2]), og = sigm(ac2[3]);
            const float c2 = fg * c_a + ig * gg;      // c_a already updated (layer-1)
            const float h2 = og * tanhf(c2);
            part = wout_s[1 + k0] * h2;
        }
        if (has_b) {
            const float ig = sigm(ac2[4]), fg = sigm(ac2[5]);
            const float gg = tanhf(ac2[6]), og = sigm(ac2[7]);
            const float c2 = fg * c_b + ig * gg;
            const float h2 = og * tanhf(c2);
            part += wout_s[33 + k0] * h2;
        }
        // reduce across the 32 lanes sharing this row (half-wave, xor stays inside)
        #pragma unroll
        for (int d = 1; d <= 16; d <<= 1)
            part += __shfl_xor(part, d, 64);
        const float outv = part + bo;
        if (k0 == 0) {
            out[row * TT + t] = outv;
            xprev[r] = outv;
        }
        __syncthreads();
    }
}

extern "C" void kernel_launch(void* const* d_in, const int* in_sizes, int n_in,
                              void* d_out, int out_size, void* d_ws, size_t ws_size,
                              hipStream_t stream) {
    (void)in_sizes; (void)n_in; (void)d_ws; (void)ws_size; (void)out_size;
    const float* x    = (const float*)d_in[0];
    const float* Wih1 = (const float*)d_in[1];
    const float* Whh1 = (const float*)d_in[2];
    const float* bih1 = (const float*)d_in[3];
    const float* bhh1 = (const float*)d_in[4];
    const float* Wih2 = (const float*)d_in[5];
    const float* Whh2 = (const float*)d_in[6];
    const float* bih2 = (const float*)d_in[7];
    const float* bhh2 = (const float*)d_in[8];
    const float* Wout = (const float*)d_in[9];
    const float* bout = (const float*)d_in[10];
    float* outp = (float*)d_out;

    dim3 grid(8192 / RPB);   // 256 blocks, 1 per CU
    dim3 block(NTH);
    hipLaunchKernelGGL(lstm_kernel, grid, block, 0, stream,
                       x, Wih1, Whh1, bih1, bhh1, Wih2, Whh2, bih2, bhh2,
                       Wout, bout, outp);
}

// Round 2
// 7807.293 us; speedup vs baseline: 4.2123x; 4.2123x over previous
//
#include <hip/hip_runtime.h>

#define HH   51
#define H4   204
#define TSEQ 2048
#define FUT  64
#define TT   (TSEQ + FUT)   // 2112
#define RPB  32             // batch rows per block
#define NTH  1024           // 16 waves
#define HSTR 72             // halfs per hbuf row (stride 144 B, 16B-aligned frag reads)
#define GSTR 220            // floats per G row (880 B: 16B-aligned float4, 2-way-max store conflicts)

typedef _Float16 h8 __attribute__((ext_vector_type(8)));
typedef float    f4 __attribute__((ext_vector_type(4)));

__device__ __forceinline__ float sigm(float z) { return 1.0f / (1.0f + __expf(-z)); }
// branch-free tanh via exp; saturates correctly at +-inf
__device__ __forceinline__ float tanh_fast(float z) { return 2.0f / (1.0f + __expf(-2.0f * z)) - 1.0f; }

__global__ __launch_bounds__(NTH)
void lstm_kernel(const float* __restrict__ x,
                 const float* __restrict__ Wih1, const float* __restrict__ Whh1,
                 const float* __restrict__ bih1, const float* __restrict__ bhh1,
                 const float* __restrict__ Wih2, const float* __restrict__ Whh2,
                 const float* __restrict__ bih2, const float* __restrict__ bhh2,
                 const float* __restrict__ Wout, const float* __restrict__ bout,
                 float* __restrict__ out)
{
    // A-operand buffer: [row][k-slot]; slot0 = x_t, slots 1..51 = h1, 52..63 = zero pad
    __shared__ _Float16 hbuf[RPB][HSTR];
    // gate pre-activations, columns reordered j' = 4k + q (q: 0=i,1=f,2=g,3=o)
    __shared__ float G[RPB][GSTR];
    __shared__ float bias1s[H4 + 4];
    __shared__ float bias2s[H4 + 4];
    __shared__ float wouts[64];

    const int tid  = threadIdx.x;
    const int lane = tid & 63;
    const int w    = tid >> 6;        // wave id 0..15
    const int quad = lane >> 4;       // 0..3
    const int nl   = lane & 15;
    const int rb   = blockIdx.x * RPB;

    // ---------------- one-time init ----------------
    for (int i = tid; i < H4; i += NTH) {
        const int kk = i >> 2, q = i & 3, j = q * HH + kk;   // gate-reorder j' -> original row
        bias1s[i] = bih1[j] + bhh1[j];
        bias2s[i] = bih2[j] + bhh2[j];
    }
    if (tid < 64) wouts[tid] = (tid < HH) ? Wout[tid] : 0.0f;
    for (int i = tid; i < RPB * HSTR; i += NTH) (&hbuf[0][0])[i] = (_Float16)0.0f;
    if (tid < RPB) hbuf[tid][0] = (_Float16)x[(size_t)(rb + tid) * TSEQ + 0];
    const float bo = bout[0];

    // ---------------- weight B-fragments (registers, once) ----------------
    // wave w < 13 owns gate n-tile w: cols j' in [16w, 16w+16)
    // B[k][n]: n = lane&15, k = quad*8 + j (per 16x16x32 fragment layout), kstep s adds 32
    h8 B1[2], B2[2];
    if (w < 13) {
        const int jp = 16 * w + nl;          // j' (reordered gate col)
        const int kk = jp >> 2, q = jp & 3;
        const bool valid = (jp < H4);
        const int jrow = q * HH + kk;        // original gate row
        #pragma unroll
        for (int s = 0; s < 2; ++s) {
            h8 b1v, b2v;
            #pragma unroll
            for (int j = 0; j < 8; ++j) {
                const int k = s * 32 + quad * 8 + j;
                float w1 = 0.0f, w2 = 0.0f;
                if (valid) {
                    if (k == 0) {
                        w1 = Wih1[jrow];                     // layer1 col0 = x weight; layer2 col0 = 0
                    } else if (k <= HH) {
                        const int o = jrow * HH + (k - 1);
                        w1 = Whh1[o];
                        w2 = Wih2[o] + Whh2[o];              // layer2: x and h are both h1
                    }
                }
                b1v[j] = (_Float16)w1;
                b2v[j] = (_Float16)w2;
            }
            B1[s] = b1v;
            B2[s] = b2v;
        }
    }
    __syncthreads();

    // activation-phase ownership: thread handles (arow, k) and (arow+16, k)
    const int arow = tid >> 6;   // 0..15 (== wave id; wave-local reduce per row)
    const int kact = tid & 63;   // 0..63, valid work for k < 51
    float c_a = 0.0f, c_b = 0.0f;

    for (int t = 0; t < TT; ++t) {
        // prefetch next x (wave 15 idles during MFMA)
        float xpre = 0.0f;
        if (w == 15 && lane < RPB && (t + 1) < TSEQ)
            xpre = x[(size_t)(rb + lane) * TSEQ + (t + 1)];

        // ---------------- layer 1 MFMA ----------------
        if (w < 13) {
            h8 A0[2], A1[2];
            #pragma unroll
            for (int s = 0; s < 2; ++s) {
                A0[s] = *(const h8*)&hbuf[nl][s * 32 + quad * 8];
                A1[s] = *(const h8*)&hbuf[16 + nl][s * 32 + quad * 8];
            }
            f4 c0 = {0.f, 0.f, 0.f, 0.f}, c1 = {0.f, 0.f, 0.f, 0.f};
            c0 = __builtin_amdgcn_mfma_f32_16x16x32_f16(A0[0], B1[0], c0, 0, 0, 0);
            c0 = __builtin_amdgcn_mfma_f32_16x16x32_f16(A0[1], B1[1], c0, 0, 0, 0);
            c1 = __builtin_amdgcn_mfma_f32_16x16x32_f16(A1[0], B1[0], c1, 0, 0, 0);
            c1 = __builtin_amdgcn_mfma_f32_16x16x32_f16(A1[1], B1[1], c1, 0, 0, 0);
            #pragma unroll
            for (int r = 0; r < 4; ++r) {          // C/D: col = lane&15, row = quad*4 + r
                G[quad * 4 + r][16 * w + nl]      = c0[r];
                G[16 + quad * 4 + r][16 * w + nl] = c1[r];
            }
        }
        __syncthreads();

        // ---------------- layer 1 activations ----------------
        if (kact < HH) {
            const f4 ga = *(const f4*)&G[arow][4 * kact];
            const float ia = sigm(ga[0] + bias1s[4 * kact]);
            const float fa = sigm(ga[1] + bias1s[4 * kact + 1]);
            const float gg = tanh_fast(ga[2] + bias1s[4 * kact + 2]);
            const float oa = sigm(ga[3] + bias1s[4 * kact + 3]);
            c_a = fa * c_a + ia * gg;
            hbuf[arow][1 + kact] = (_Float16)(oa * tanh_fast(c_a));

            const f4 gb = *(const f4*)&G[arow + 16][4 * kact];
            const float ib = sigm(gb[0] + bias1s[4 * kact]);
            const float fb = sigm(gb[1] + bias1s[4 * kact + 1]);
            const float gb2 = tanh_fast(gb[2] + bias1s[4 * kact + 2]);
            const float ob = sigm(gb[3] + bias1s[4 * kact + 3]);
            c_b = fb * c_b + ib * gb2;
            hbuf[arow + 16][1 + kact] = (_Float16)(ob * tanh_fast(c_b));
        }
        __syncthreads();

        // ---------------- layer 2 (emit) MFMA ----------------
        if (w < 13) {
            h8 A0[2], A1[2];
            #pragma unroll
            for (int s = 0; s < 2; ++s) {
                A0[s] = *(const h8*)&hbuf[nl][s * 32 + quad * 8];
                A1[s] = *(const h8*)&hbuf[16 + nl][s * 32 + quad * 8];
            }
            f4 c0 = {0.f, 0.f, 0.f, 0.f}, c1 = {0.f, 0.f, 0.f, 0.f};
            c0 = __builtin_amdgcn_mfma_f32_16x16x32_f16(A0[0], B2[0], c0, 0, 0, 0);
            c0 = __builtin_amdgcn_mfma_f32_16x16x32_f16(A0[1], B2[1], c0, 0, 0, 0);
            c1 = __builtin_amdgcn_mfma_f32_16x16x32_f16(A1[0], B2[0], c1, 0, 0, 0);
            c1 = __builtin_amdgcn_mfma_f32_16x16x32_f16(A1[1], B2[1], c1, 0, 0, 0);
            #pragma unroll
            for (int r = 0; r < 4; ++r) {
                G[quad * 4 + r][16 * w + nl]      = c0[r];
                G[16 + quad * 4 + r][16 * w + nl] = c1[r];
            }
        }
        __syncthreads();

        // ---------------- layer 2 activations + output ----------------
        float pa = 0.0f, pb = 0.0f;
        if (kact < HH) {
            const f4 ga = *(const f4*)&G[arow][4 * kact];
            const float ia = sigm(ga[0] + bias2s[4 * kact]);
            const float fa = sigm(ga[1] + bias2s[4 * kact + 1]);
            const float gg = tanh_fast(ga[2] + bias2s[4 * kact + 2]);
            const float oa = sigm(ga[3] + bias2s[4 * kact + 3]);
            const float c2a = fa * c_a + ia * gg;            // uses layer-1-updated c
            pa = oa * tanh_fast(c2a) * wouts[kact];

            const f4 gb = *(const f4*)&G[arow + 16][4 * kact];
            const float ib = sigm(gb[0] + bias2s[4 * kact]);
            const float fb = sigm(gb[1] + bias2s[4 * kact + 1]);
            const float gb2 = tanh_fast(gb[2] + bias2s[4 * kact + 2]);
            const float ob = sigm(gb[3] + bias2s[4 * kact + 3]);
            const float c2b = fb * c_b + ib * gb2;
            pb = ob * tanh_fast(c2b) * wouts[kact];
        }
        #pragma unroll
        for (int d = 1; d < 64; d <<= 1) {
            pa += __shfl_xor(pa, d, 64);
            pb += __shfl_xor(pb, d, 64);
        }
        if (lane == 0) {
            const float oa = pa + bo, ob = pb + bo;
            out[(size_t)(rb + arow) * TT + t]      = oa;
            out[(size_t)(rb + arow + 16) * TT + t] = ob;
            if (t + 1 >= TSEQ) {                    // autoregressive feedback
                hbuf[arow][0]      = (_Float16)oa;
                hbuf[arow + 16][0] = (_Float16)ob;
            }
        }
        if (w == 15 && lane < RPB && (t + 1) < TSEQ)
            hbuf[lane][0] = (_Float16)xpre;
        __syncthreads();
    }
}

extern "C" void kernel_launch(void* const* d_in, const int* in_sizes, int n_in,
                              void* d_out, int out_size, void* d_ws, size_t ws_size,
                              hipStream_t stream) {
    (void)in_sizes; (void)n_in; (void)d_ws; (void)ws_size; (void)out_size;
    const float* x    = (const float*)d_in[0];
    const float* Wih1 = (const float*)d_in[1];
    const float* Whh1 = (const float*)d_in[2];
    const float* bih1 = (const float*)d_in[3];
    const float* bhh1 = (const float*)d_in[4];
    const float* Wih2 = (const float*)d_in[5];
    const float* Whh2 = (const float*)d_in[6];
    const float* bih2 = (const float*)d_in[7];
    const float* bhh2 = (const float*)d_in[8];
    const float* Wout = (const float*)d_in[9];
    const float* bout = (const float*)d_in[10];
    float* outp = (float*)d_out;

    dim3 grid(8192 / RPB);   // 256 blocks, 1 per CU
    dim3 block(NTH);
    hipLaunchKernelGGL(lstm_kernel, grid, block, 0, stream,
                       x, Wih1, Whh1, bih1, bhh1, Wih2, Whh2, bih2, bhh2,
                       Wout, bout, outp);
}

// Round 3
// 4036.625 us; speedup vs baseline: 8.1470x; 1.9341x over previous
//
#include <hip/hip_runtime.h>

#define HH   51
#define H4   204
#define TSEQ 2048
#define FUT  64
#define TT   (TSEQ + FUT)   // 2112
#define RPB  16             // batch rows per block (2 blocks/CU)
#define NTH  1024           // 16 waves
#define HSTR 72             // halfs per hbuf row (144 B stride, 16B-aligned frag reads)
#define GSTR 220            // floats per G row (880 B stride, 16B-aligned f4)

typedef _Float16 h8 __attribute__((ext_vector_type(8)));
typedef float    f4 __attribute__((ext_vector_type(4)));

#define LOG2E 1.44269504f

// branch-free, division-free: v_exp_f32 + v_rcp_f32 (~1 ulp each)
__device__ __forceinline__ float sigm_f(float z) {
    return __builtin_amdgcn_rcpf(1.0f + __builtin_amdgcn_exp2f(-LOG2E * z));
}
__device__ __forceinline__ float tanh_f(float z) {
    return __builtin_fmaf(2.0f,
        __builtin_amdgcn_rcpf(1.0f + __builtin_amdgcn_exp2f(-2.0f * LOG2E * z)), -1.0f);
}

__global__ __launch_bounds__(NTH, 8)
void lstm_kernel(const float* __restrict__ x,
                 const float* __restrict__ Wih1, const float* __restrict__ Whh1,
                 const float* __restrict__ bih1, const float* __restrict__ bhh1,
                 const float* __restrict__ Wih2, const float* __restrict__ Whh2,
                 const float* __restrict__ bih2, const float* __restrict__ bhh2,
                 const float* __restrict__ Wout, const float* __restrict__ bout,
                 float* __restrict__ out)
{
    // A-operand: [row][k]; k=0: x_t, k=1..51: h1, k=52,53: constant 1 (bias hi/lo), rest 0
    __shared__ _Float16 hbuf[RPB][HSTR];
    // gate pre-activations WITH bias folded in, cols reordered j' = 4k + q (i,f,g,o)
    __shared__ float G[RPB][GSTR];
    __shared__ float wouts[64];

    const int tid  = threadIdx.x;
    const int lane = tid & 63;
    const int w    = tid >> 6;        // wave id 0..15
    const int quad = lane >> 4;       // 0..3
    const int nl   = lane & 15;
    const int rb   = blockIdx.x * RPB;

    // ---------------- one-time init ----------------
    if (tid < 64) wouts[tid] = (tid < HH) ? Wout[tid] : 0.0f;
    for (int i = tid; i < RPB * HSTR; i += NTH) (&hbuf[0][0])[i] = (_Float16)0.0f;
    if (tid < RPB) {
        hbuf[tid][0]  = (_Float16)x[(size_t)(rb + tid) * TSEQ + 0];
        hbuf[tid][52] = (_Float16)1.0f;   // bias-hi slot
        hbuf[tid][53] = (_Float16)1.0f;   // bias-lo slot
    }
    const float bo = bout[0];

    // ---------------- weight B-fragments in registers (once) ----------------
    // wave w < 13 owns gate n-tile w: cols j' in [16w, 16w+16)
    // B[k][n]: n = lane&15, k = quad*8 + j; k-slice s adds 32
    h8 B1[2], B2[2];
    if (w < 13) {
        const int jp = 16 * w + nl;          // reordered gate col
        const int kk = jp >> 2, q = jp & 3;
        const bool valid = (jp < H4);
        const int jrow = q * HH + kk;        // original gate row
        float b1 = 0.0f, b2 = 0.0f;
        if (valid) { b1 = bih1[jrow] + bhh1[jrow]; b2 = bih2[jrow] + bhh2[jrow]; }
        const _Float16 b1h = (_Float16)b1, b2h = (_Float16)b2;
        const _Float16 b1l = (_Float16)(b1 - (float)b1h), b2l = (_Float16)(b2 - (float)b2h);
        #pragma unroll
        for (int s = 0; s < 2; ++s) {
            h8 b1v, b2v;
            #pragma unroll
            for (int j = 0; j < 8; ++j) {
                const int k = s * 32 + quad * 8 + j;
                _Float16 w1 = (_Float16)0.0f, w2 = (_Float16)0.0f;
                if (valid) {
                    if (k == 0) {
                        w1 = (_Float16)Wih1[jrow];
                    } else if (k <= HH) {
                        const int o = jrow * HH + (k - 1);
                        w1 = (_Float16)Whh1[o];
                        w2 = (_Float16)(Wih2[o] + Whh2[o]);
                    } else if (k == 52) { w1 = b1h; w2 = b2h; }
                    else if (k == 53)   { w1 = b1l; w2 = b2l; }
                }
                b1v[j] = w1;
                b2v[j] = w2;
            }
            B1[s] = b1v;
            B2[s] = b2v;
        }
    }
    __syncthreads();

    const int kact = tid & 63;   // activation element; valid for kact < 51; row = w
    float c_a = 0.0f;

    for (int t = 0; t < TT; ++t) {
        // prefetch next x (consumed at loop bottom; vmcnt hidden across the step)
        float xpre = 0.0f;
        if (w == 15 && lane < RPB && (t + 1) < TSEQ)
            xpre = x[(size_t)(rb + lane) * TSEQ + (t + 1)];

        // ---------------- layer 1 MFMA ----------------
        if (w < 13) {
            h8 A0[2];
            #pragma unroll
            for (int s = 0; s < 2; ++s)
                A0[s] = *(const h8*)&hbuf[nl][s * 32 + quad * 8];
            f4 c0 = {0.f, 0.f, 0.f, 0.f};
            c0 = __builtin_amdgcn_mfma_f32_16x16x32_f16(A0[0], B1[0], c0, 0, 0, 0);
            c0 = __builtin_amdgcn_mfma_f32_16x16x32_f16(A0[1], B1[1], c0, 0, 0, 0);
            #pragma unroll
            for (int r = 0; r < 4; ++r)            // C/D: col = lane&15, row = quad*4 + r
                G[quad * 4 + r][16 * w + nl] = c0[r];
        }
        __syncthreads();

        // ---------------- layer 1 activations ----------------
        if (kact < HH) {
            const f4 g = *(const f4*)&G[w][4 * kact];
            const float ia = sigm_f(g[0]);
            const float fa = sigm_f(g[1]);
            const float ga = tanh_f(g[2]);
            const float oa = sigm_f(g[3]);
            c_a = fa * c_a + ia * ga;
            hbuf[w][1 + kact] = (_Float16)(oa * tanh_f(c_a));
        }
        __syncthreads();

        // ---------------- layer 2 (emit) MFMA ----------------
        if (w < 13) {
            h8 A0[2];
            #pragma unroll
            for (int s = 0; s < 2; ++s)
                A0[s] = *(const h8*)&hbuf[nl][s * 32 + quad * 8];
            f4 c0 = {0.f, 0.f, 0.f, 0.f};
            c0 = __builtin_amdgcn_mfma_f32_16x16x32_f16(A0[0], B2[0], c0, 0, 0, 0);
            c0 = __builtin_amdgcn_mfma_f32_16x16x32_f16(A0[1], B2[1], c0, 0, 0, 0);
            #pragma unroll
            for (int r = 0; r < 4; ++r)
                G[quad * 4 + r][16 * w + nl] = c0[r];
        }
        __syncthreads();

        // ---------------- layer 2 activations + output ----------------
        float p = 0.0f;
        if (kact < HH) {
            const f4 g = *(const f4*)&G[w][4 * kact];
            const float ia = sigm_f(g[0]);
            const float fa = sigm_f(g[1]);
            const float ga = tanh_f(g[2]);
            const float oa = sigm_f(g[3]);
            const float c2 = fa * c_a + ia * ga;     // uses layer-1-updated c_a
            p = oa * tanh_f(c2) * wouts[kact];
        }
        #pragma unroll
        for (int d = 1; d < 64; d <<= 1)
            p += __shfl_xor(p, d, 64);
        if (lane == 0) {
            const float ov = p + bo;
            out[(size_t)(rb + w) * TT + t] = ov;
            if (t + 1 >= TSEQ)                       // autoregressive feedback
                hbuf[w][0] = (_Float16)ov;
        }
        if (w == 15 && lane < RPB && (t + 1) < TSEQ)
            hbuf[lane][0] = (_Float16)xpre;
        __syncthreads();
    }
}

extern "C" void kernel_launch(void* const* d_in, const int* in_sizes, int n_in,
                              void* d_out, int out_size, void* d_ws, size_t ws_size,
                              hipStream_t stream) {
    (void)in_sizes; (void)n_in; (void)d_ws; (void)ws_size; (void)out_size;
    const float* x    = (const float*)d_in[0];
    const float* Wih1 = (const float*)d_in[1];
    const float* Whh1 = (const float*)d_in[2];
    const float* bih1 = (const float*)d_in[3];
    const float* bhh1 = (const float*)d_in[4];
    const float* Wih2 = (const float*)d_in[5];
    const float* Whh2 = (const float*)d_in[6];
    const float* bih2 = (const float*)d_in[7];
    const float* bhh2 = (const float*)d_in[8];
    const float* Wout = (const float*)d_in[9];
    const float* bout = (const float*)d_in[10];
    float* outp = (float*)d_out;

    dim3 grid(8192 / RPB);   // 512 blocks, 2 per CU
    dim3 block(NTH);
    hipLaunchKernelGGL(lstm_kernel, grid, block, 0, stream,
                       x, Wih1, Whh1, bih1, bhh1, Wih2, Whh2, bih2, bhh2,
                       Wout, bout, outp);
}

// Round 4
// 2956.572 us; speedup vs baseline: 11.1232x; 1.3653x over previous
//
#include <hip/hip_runtime.h>

#define HH   51
#define H4   204
#define TSEQ 2048
#define FUT  64
#define TT   (TSEQ + FUT)   // 2112
#define RPB  16             // batch rows per block (2 blocks/CU)
#define NTH  1024           // 16 waves: 0..12 MFMA+act, 13 out-emit, 14 x-prefetch, 15 idle
#define HSTR 80             // halfs per hbuf row (160 B stride: 16B-aligned, 4-way max conflict)

typedef _Float16 h8 __attribute__((ext_vector_type(8)));
typedef float    f4 __attribute__((ext_vector_type(4)));

#define LOG2E 1.44269504f

__device__ __forceinline__ float sigm_f(float z) {
    return __builtin_amdgcn_rcpf(1.0f + __builtin_amdgcn_exp2f(-LOG2E * z));
}
__device__ __forceinline__ float tanh_f(float z) {
    return __builtin_fmaf(2.0f,
        __builtin_amdgcn_rcpf(1.0f + __builtin_amdgcn_exp2f(-2.0f * LOG2E * z)), -1.0f);
}

__global__ __launch_bounds__(NTH, 8)
void lstm_kernel(const float* __restrict__ x,
                 const float* __restrict__ Wih1, const float* __restrict__ Whh1,
                 const float* __restrict__ bih1, const float* __restrict__ bhh1,
                 const float* __restrict__ Wih2, const float* __restrict__ Whh2,
                 const float* __restrict__ bih2, const float* __restrict__ bhh2,
                 const float* __restrict__ Wout, const float* __restrict__ bout,
                 float* __restrict__ out)
{
    // double-buffered B-operand: [buf][row][k]; k=0: x_t, 1..51: h1, 52,53: const 1 (bias hi/lo)
    __shared__ _Float16 hbuf[2][RPB][HSTR];
    // per-wave partial sums of wout.h2, double-buffered: [buf][wave][row]
    __shared__ float part[2][13][17];
    __shared__ float wouts[64];

    const int tid  = threadIdx.x;
    const int lane = tid & 63;
    const int w    = tid >> 6;        // wave id
    const int quad = lane >> 4;       // 0..3
    const int nl   = lane & 15;       // batch row (B-operand n / C-D col)
    const int rb   = blockIdx.x * RPB;

    // ---------------- one-time init ----------------
    if (tid < 64) wouts[tid] = (tid < HH) ? Wout[tid] : 0.0f;
    for (int i = tid; i < 2 * RPB * HSTR; i += NTH) (&hbuf[0][0][0])[i] = (_Float16)0.0f;
    __syncthreads();
    if (tid < RPB) {
        hbuf[0][tid][0]  = (_Float16)x[(size_t)(rb + tid) * TSEQ];
        hbuf[0][tid][52] = (_Float16)1.0f;  hbuf[0][tid][53] = (_Float16)1.0f;
        hbuf[1][tid][52] = (_Float16)1.0f;  hbuf[1][tid][53] = (_Float16)1.0f;
    }
    const float bo = bout[0];

    // ---------------- weight A-fragments in registers (once) ----------------
    // wave w<13 owns gate m-tile w: rows j' = 16w..16w+15 (j' = 4k+q interleave)
    // A[m][k]: m = lane&15 -> j' = 16w+nl, k = 32s + quad*8 + j
    h8 W1[2], W2[2];
    if (w < 13) {
        const int jp = 16 * w + nl;
        const int kk = jp >> 2, q = jp & 3;
        const bool valid = (jp < H4);
        const int jrow = q * HH + kk;        // original gate row
        float b1 = 0.0f, b2 = 0.0f;
        if (valid) { b1 = bih1[jrow] + bhh1[jrow]; b2 = bih2[jrow] + bhh2[jrow]; }
        const _Float16 b1h = (_Float16)b1, b2h = (_Float16)b2;
        const _Float16 b1l = (_Float16)(b1 - (float)b1h), b2l = (_Float16)(b2 - (float)b2h);
        #pragma unroll
        for (int s = 0; s < 2; ++s) {
            h8 w1v, w2v;
            #pragma unroll
            for (int j = 0; j < 8; ++j) {
                const int k = s * 32 + quad * 8 + j;
                _Float16 a1 = (_Float16)0.0f, a2 = (_Float16)0.0f;
                if (valid) {
                    if (k == 0) {
                        a1 = (_Float16)Wih1[jrow];
                    } else if (k <= HH) {
                        const int o = jrow * HH + (k - 1);
                        a1 = (_Float16)Whh1[o];
                        a2 = (_Float16)(Wih2[o] + Whh2[o]);
                    } else if (k == 52) { a1 = b1h; a2 = b2h; }
                    else if (k == 53)   { a1 = b1l; a2 = b2l; }
                }
                w1v[j] = a1;
                w2v[j] = a2;
            }
            W1[s] = w1v;
            W2[s] = w2v;
        }
    }

    // x register pipeline (wave 14): xnext = x(t+1) at top of step t
    float xnext = 0.0f;
    if (w == 14 && lane < RPB) xnext = x[(size_t)(rb + lane) * TSEQ + 1];

    // this lane owns element (row = nl, k = kh) for waves < 13
    const int kh = 4 * w + quad;
    float c1 = 0.0f;
    __syncthreads();

    for (int t = 0; t < TT; ++t) {
        const int cur = t & 1, nxt = cur ^ 1;

        // ================= Phase 1: L1 recurrence (+ overlapped emit/prefetch) =================
        if (w < 13) {
            const h8 Bh0 = *(const h8*)&hbuf[cur][nl][quad * 8];
            const h8 Bh1 = *(const h8*)&hbuf[cur][nl][32 + quad * 8];
            f4 g = {0.f, 0.f, 0.f, 0.f};
            g = __builtin_amdgcn_mfma_f32_16x16x32_f16(W1[0], Bh0, g, 0, 0, 0);
            g = __builtin_amdgcn_mfma_f32_16x16x32_f16(W1[1], Bh1, g, 0, 0, 0);
            // D: col = nl = batch row, rowreg r = gate q of k = kh  -> all 4 gates in-lane
            const float ig = sigm_f(g[0]);
            const float fg = sigm_f(g[1]);
            const float gg = tanh_f(g[2]);
            const float og = sigm_f(g[3]);
            c1 = fg * c1 + ig * gg;
            const float h1v = og * tanh_f(c1);
            if (kh < HH) hbuf[nxt][nl][1 + kh] = (_Float16)h1v;
        } else if (w == 13) {
            // emit out(t-1) from part written in phase 2 of step t-1
            if (t >= 1 && t <= TSEQ - 1 && lane < RPB) {
                float s = bo;
                #pragma unroll
                for (int j = 0; j < 13; ++j) s += part[cur ^ 1][j][lane];
                out[(size_t)(rb + lane) * TT + (t - 1)] = s;
            }
        } else if (w == 14) {
            if (lane < RPB) {
                if (t + 1 < TSEQ) hbuf[nxt][lane][0] = (_Float16)xnext;
                if (t + 2 < TSEQ) xnext = x[(size_t)(rb + lane) * TSEQ + (t + 2)];
            }
        }
        __syncthreads();

        // ================= Phase 2: L2 emit GEMM + act =================
        if (w < 13) {
            const h8 Bh0 = *(const h8*)&hbuf[nxt][nl][quad * 8];
            const h8 Bh1 = *(const h8*)&hbuf[nxt][nl][32 + quad * 8];
            f4 g = {0.f, 0.f, 0.f, 0.f};
            g = __builtin_amdgcn_mfma_f32_16x16x32_f16(W2[0], Bh0, g, 0, 0, 0);
            g = __builtin_amdgcn_mfma_f32_16x16x32_f16(W2[1], Bh1, g, 0, 0, 0);
            const float ig = sigm_f(g[0]);
            const float fg = sigm_f(g[1]);
            const float gg = tanh_f(g[2]);
            const float og = sigm_f(g[3]);
            const float c2 = fg * c1 + ig * gg;     // c input is current c1 (per reference emit)
            float p = og * tanh_f(c2) * wouts[kh];  // wouts[51] = 0 masks the invalid lane
            p += __shfl_xor(p, 16, 64);             // reduce over quad (k within wave)
            p += __shfl_xor(p, 32, 64);
            if (quad == 0) part[cur][w][nl] = p;
        }
        __syncthreads();

        // ================= FUT steps: in-step emit + feedback =================
        if (t >= TSEQ - 1) {
            if (w == 13 && lane < RPB) {
                float s = bo;
                #pragma unroll
                for (int j = 0; j < 13; ++j) s += part[cur][j][lane];
                out[(size_t)(rb + lane) * TT + t] = s;
                hbuf[nxt][lane][0] = (_Float16)s;   // autoregressive x(t+1)
            }
            __syncthreads();
        }
    }
}

extern "C" void kernel_launch(void* const* d_in, const int* in_sizes, int n_in,
                              void* d_out, int out_size, void* d_ws, size_t ws_size,
                              hipStream_t stream) {
    (void)in_sizes; (void)n_in; (void)d_ws; (void)ws_size; (void)out_size;
    const float* x    = (const float*)d_in[0];
    const float* Wih1 = (const float*)d_in[1];
    const float* Whh1 = (const float*)d_in[2];
    const float* bih1 = (const float*)d_in[3];
    const float* bhh1 = (const float*)d_in[4];
    const float* Wih2 = (const float*)d_in[5];
    const float* Whh2 = (const float*)d_in[6];
    const float* bih2 = (const float*)d_in[7];
    const float* bhh2 = (const float*)d_in[8];
    const float* Wout = (const float*)d_in[9];
    const float* bout = (const float*)d_in[10];
    float* outp = (float*)d_out;

    dim3 grid(8192 / RPB);   // 512 blocks, 2 per CU
    dim3 block(NTH);
    hipLaunchKernelGGL(lstm_kernel, grid, block, 0, stream,
                       x, Wih1, Whh1, bih1, bhh1, Wih2, Whh2, bih2, bhh2,
                       Wout, bout, outp);
}